// Round 15
// baseline (872.036 us; speedup 1.0000x reference)
//
#include <hip/hip_runtime.h>
#include <math.h>

#define B_   64
#define T_   128
#define NIN  256
#define H_   512
#define O_   256
#define M_   64
#define R_   512
#define EPS_ 1e-8f

typedef _Float16 h2 __attribute__((ext_vector_type(2)));
typedef _Float16 f16x8 __attribute__((ext_vector_type(8)));
typedef float f32x4 __attribute__((ext_vector_type(4)));

__device__ __forceinline__ float dot4(float4 a, float4 b) {
    return a.x*b.x + a.y*b.y + a.z*b.z + a.w*b.w;
}

__device__ __forceinline__ float frcp(float x) {
#if __has_builtin(__builtin_amdgcn_rcpf)
    return __builtin_amdgcn_rcpf(x);
#else
    return 1.f / x;
#endif
}
__device__ __forceinline__ float fsqrt_(float x) {
#if __has_builtin(__builtin_amdgcn_sqrtf)
    return __builtin_amdgcn_sqrtf(x);
#else
    return sqrtf(x);
#endif
}

__device__ __forceinline__ float fd2(unsigned wu, unsigned hu, float acc) {
#if __has_builtin(__builtin_amdgcn_fdot2)
    return __builtin_amdgcn_fdot2(__builtin_bit_cast(h2, wu),
                                  __builtin_bit_cast(h2, hu), acc, false);
#else
    h2 w = __builtin_bit_cast(h2, wu), h = __builtin_bit_cast(h2, hu);
    return acc + (float)w[0]*(float)h[0] + (float)w[1]*(float)h[1];
#endif
}
#define FD4(W, HX, A) { A = fd2(W.x, HX.x, A); A = fd2(W.y, HX.y, A); \
                        A = fd2(W.z, HX.z, A); A = fd2(W.w, HX.w, A); }

__device__ __forceinline__ unsigned pk16(float a, float b) {
    return __builtin_bit_cast(unsigned, __builtin_amdgcn_cvt_pkrtz(a, b));
}
__device__ __forceinline__ unsigned short bits16(float v) {
    return __builtin_bit_cast(unsigned short, (_Float16)v);
}

template<int CTRL>
__device__ __forceinline__ float dpp_add(float v) {
    int t = __builtin_amdgcn_update_dpp(0, __float_as_int(v), CTRL, 0xF, 0xF, false);
    return v + __int_as_float(t);
}
template<int CTRL>
__device__ __forceinline__ float dpp_mov(float v) {
    return __int_as_float(__builtin_amdgcn_update_dpp(0, __float_as_int(v), CTRL, 0xF, 0xF, false));
}
__device__ __forceinline__ float red16(float v) {
    v = dpp_add<0xB1>(v);    // quad_perm xor1
    v = dpp_add<0x4E>(v);    // quad_perm xor2
    v = dpp_add<0x124>(v);   // row_ror:4
    v = dpp_add<0x128>(v);   // row_ror:8
    return v;
}
__device__ __forceinline__ float red64_pair(float v) {
    v = dpp_add<0x4E>(v);    // xor2
    v = dpp_add<0x124>(v);   // ror4
    v = dpp_add<0x128>(v);   // ror8
    v += __shfl_xor(v, 16, 64);
    v += __shfl_xor(v, 32, 64);
    return v;
}
__device__ __forceinline__ float sigmoid_f(float x) { return frcp(1.f + __expf(-x)); }
__device__ __forceinline__ float softplus_f(float x){ return x > 20.f ? x : log1pf(__expf(x)); }

// ---------- Kernel 0: all fp32 -> fp16 conversions in one launch ----------
// blocks 0..2047: x (2 MB f32 -> xh); 2048..2175: Win; 2176..2303: Wout;
// 2304..2431: proj matrices -> Wh; 2432: scalar-head rows.
__global__ __launch_bounds__(256) void prep(
    const float* __restrict__ x, const float* __restrict__ Win,
    const float* __restrict__ Wout,
    const float* __restrict__ Wkr, const float* __restrict__ Wkw,
    const float* __restrict__ We,  const float* __restrict__ Wa,
    const float* __restrict__ Wbr, const float* __restrict__ Wgr,
    const float* __restrict__ Wbw, const float* __restrict__ Wgw,
    unsigned short* __restrict__ xh, unsigned short* __restrict__ Winh,
    unsigned short* __restrict__ Wouth, unsigned short* __restrict__ Wh)
{
    const int bid = blockIdx.x;
    if (bid == 2432) {   // scalar-head rows 256..259 of Wh
        const int idx = threadIdx.x * 8;
        #pragma unroll
        for (int k = 0; k < 8; ++k) {
            int i2 = idx + k;
            int mi2 = i2 >> 9;
            const float* s2 = mi2 == 0 ? Wbr : mi2 == 1 ? Wgr : mi2 == 2 ? Wbw : Wgw;
            Wh[256 * H_ + i2] = bits16(s2[i2 & (H_ - 1)]);
        }
        return;
    }
    const float* src; unsigned short* dst; int idx;
    if (bid < 2048)      { src = x;    dst = xh;    idx = bid * 1024 + threadIdx.x * 4; }
    else if (bid < 2176) { src = Win;  dst = Winh;  idx = (bid - 2048) * 1024 + threadIdx.x * 4; }
    else if (bid < 2304) { src = Wout; dst = Wouth; idx = (bid - 2176) * 1024 + threadIdx.x * 4; }
    else {
        const int mi = (bid - 2304) >> 5;
        src = mi == 0 ? Wkr : mi == 1 ? Wkw : mi == 2 ? We : Wa;
        dst = Wh + mi * 32768;
        idx = ((bid - 2304) & 31) * 1024 + threadIdx.x * 4;
    }
    float4 v = *(const float4*)&src[idx];
    ushort4 o;
    o.x = bits16(v.x); o.y = bits16(v.y); o.z = bits16(v.z); o.w = bits16(v.w);
    *(ushort4*)&dst[idx] = o;
}

// ---------- MFMA GEMM: C[M,N] = A_h[M,K] @ B_h[N,K]^T (+bias, opt sigmoid) ----------
__global__ __launch_bounds__(256) void gemm_mfma(
    const unsigned short* __restrict__ Ah, const unsigned short* __restrict__ Bh,
    const float* __restrict__ bias, void* __restrict__ outp,
    int M, int K, int N, int mode)
{
    const int tid  = threadIdx.x;
    const int wv   = tid >> 6, lane = tid & 63;
    const int m0   = blockIdx.x * 128 + wv * 32;
    const int n0   = blockIdx.y * 64;
    const int fr   = lane & 15, kg = lane >> 4;

    f32x4 acc[2][4] = {};
    const unsigned short* pa0 = Ah + (size_t)(m0 + fr) * K + kg * 8;
    const unsigned short* pa1 = pa0 + (size_t)16 * K;
    const unsigned short* pb  = Bh + (size_t)(n0 + fr) * K + kg * 8;

    for (int k0 = 0; k0 < K; k0 += 32) {
        f16x8 a0 = *(const f16x8*)(pa0 + k0);
        f16x8 a1 = *(const f16x8*)(pa1 + k0);
        #pragma unroll
        for (int j = 0; j < 4; ++j) {
            f16x8 bj = *(const f16x8*)(pb + (size_t)j * 16 * K + k0);
            acc[0][j] = __builtin_amdgcn_mfma_f32_16x16x32_f16(a0, bj, acc[0][j], 0, 0, 0);
            acc[1][j] = __builtin_amdgcn_mfma_f32_16x16x32_f16(a1, bj, acc[1][j], 0, 0, 0);
        }
    }
    #pragma unroll
    for (int j = 0; j < 4; ++j) {
        const int gcol = n0 + j * 16 + fr;
        const float bv = bias[gcol];
        #pragma unroll
        for (int i = 0; i < 2; ++i) {
            #pragma unroll
            for (int r = 0; r < 4; ++r) {
                const int grow = m0 + i * 16 + kg * 4 + r;
                float v = acc[i][j][r] + bv;
                if (mode == 0)
                    ((unsigned short*)outp)[(size_t)grow * N + gcol] = bits16(v);
                else
                    ((float*)outp)[(size_t)grow * N + gcol] = sigmoid_f(v);
            }
        }
    }
}

// ---------- Kernel 2: recurrent loop, 512 threads (8 waves) ----------
__global__ __launch_bounds__(512, 2) void ntm_loop(
    const unsigned short* __restrict__ xin_h,
    const float* __restrict__ h0,
    const float* __restrict__ frf0, const float* __restrict__ fwf0,
    const float* __restrict__ m0,
    const unsigned short* __restrict__ Wh,      // fp16 [256 proj rows; 4 head rows]
    const float* __restrict__ bkr_g, const float* __restrict__ bkw_g,
    const float* __restrict__ be_g,  const float* __restrict__ ba_g,
    const float* __restrict__ bbr_g, const float* __restrict__ bgr_g,
    const float* __restrict__ bbw_g, const float* __restrict__ bgw_g,
    const float* __restrict__ Wread, const float* __restrict__ bread_g,
    unsigned short* __restrict__ h_all)
{
    __shared__ __align__(16) unsigned short hh40[16 * 40];  // fp16 h, stride-40 rows
    __shared__ __align__(16) unsigned wrh[R_ * 36];         // fp16 Wread, stride-36 (72 KB)
    __shared__ __align__(16) float2 ffb[2][R_];             // {frf,fwf} double buffer (8 KB)
    __shared__ __align__(16) float2 dotsRW[R_];             // {eR,eW} (4 KB)
    __shared__ __align__(16) float2 fwp[R_];                // {w_read,w_write} (4 KB)
    __shared__ __align__(16) float proj4[4 * M_];           // kR|kW|eV|aV flat [256]
    __shared__ __align__(16) float rtp[M_][8];              // rt partials, transposed (2 KB)
    __shared__ __align__(16) float rt8[8][M_];              // per-wave reduced rt (2 KB)
    __shared__ __align__(16) float2 wsumRW[16];             // [8..15] stay zero
    __shared__ __align__(16) float bias256[4 * M_];
    __shared__ __align__(16) unsigned wheadu[4 * H_ / 2];   // 4 head rows fp16 (4 KB)
    __shared__ float bhead[4];
    __shared__ float scal[4];   // beta_r, g_r, beta_w, g_w

    const int b    = blockIdx.x;
    const int tid  = threadIdx.x;
    const int wave = tid >> 6, lane = tid & 63;
    const int g    = lane >> 4, sub = lane & 15;
    const int group = tid >> 4, s16 = tid & 15;   // phase-A: 32 groups x 16 lanes

    // ---- init ----
    const float* mg = m0 + (size_t)b * (R_ * M_);
    float4 mreg[16];                            // 64 regs: rows wave*64 + i*4 + g
    #pragma unroll
    for (int i = 0; i < 16; ++i)
        mreg[i] = *(const float4*)&mg[(wave * 64 + i * 4 + g) * M_ + sub * 4];

    // projection weights in registers: 8 passes x 4 uint4 = 128 regs
    uint4 w16[32];
    #pragma unroll
    for (int p = 0; p < 8; ++p)
        #pragma unroll
        for (int j = 0; j < 4; ++j)
            w16[p * 4 + j] = *(const uint4*)&Wh[(size_t)(p * 32 + group) * H_ + s16 * 32 + j * 8];

    hh40[(tid >> 5) * 40 + (tid & 31)] = bits16(h0[b * H_ + tid]);
    ffb[0][tid] = make_float2(frf0[b * R_ + tid], fwf0[b * R_ + tid]);
    if (tid < M_) {
        bias256[tid]          = bkr_g[tid];
        bias256[M_ + tid]     = bkw_g[tid];
        bias256[2 * M_ + tid] = be_g[tid];
        bias256[3 * M_ + tid] = ba_g[tid];
    }
    if (tid >= 8 && tid < 16) wsumRW[tid] = make_float2(0.f, 0.f);
    wheadu[tid * 2]     = ((const unsigned*)&Wh[256 * H_])[tid * 2];
    wheadu[tid * 2 + 1] = ((const unsigned*)&Wh[256 * H_])[tid * 2 + 1];
    if (tid < 4) bhead[tid] = (tid == 0 ? bbr_g : tid == 1 ? bgr_g : tid == 2 ? bbw_g : bgw_g)[0];

    // Wread -> LDS fp16, stride-36 rows; one full row per thread
    {
        const float* wrp = Wread + (size_t)tid * M_;
        #pragma unroll
        for (int wd = 0; wd < 2; ++wd)
            #pragma unroll
            for (int c = 0; c < 4; ++c) {
                float4 wa = *(const float4*)&wrp[wd * 32 + c * 8];
                float4 wb = *(const float4*)&wrp[wd * 32 + c * 8 + 4];
                uint4 o;
                o.x = pk16(wa.x, wa.y); o.y = pk16(wa.z, wa.w);
                o.z = pk16(wb.x, wb.y); o.w = pk16(wb.z, wb.w);
                *(uint4*)&wrh[tid * 36 + wd * 16 + c * 4] = o;
            }
    }
    const float breg = bread_g[tid];
    __syncthreads();

    for (int t = 0; t < T_; ++t) {
        const int cur = t & 1, nxt = cur ^ 1;

        // ---- Phase A: 8-pass projections + heads (wave 0) ----
        unsigned short xbits = xin_h[(size_t)(b * T_ + t) * H_ + tid];
        {
            uint4 hx0 = *(const uint4*)&hh40[s16 * 40 + 0];
            uint4 hx1 = *(const uint4*)&hh40[s16 * 40 + 8];
            uint4 hx2 = *(const uint4*)&hh40[s16 * 40 + 16];
            uint4 hx3 = *(const uint4*)&hh40[s16 * 40 + 24];
            float a[8];
            #pragma unroll
            for (int p = 0; p < 8; ++p) {
                float acc = 0.f;
                FD4(w16[p * 4 + 0], hx0, acc);
                FD4(w16[p * 4 + 1], hx1, acc);
                FD4(w16[p * 4 + 2], hx2, acc);
                FD4(w16[p * 4 + 3], hx3, acc);
                a[p] = red16(acc);
            }
            float av = a[0];
            #pragma unroll
            for (int p = 1; p < 8; ++p) av = (s16 == p) ? a[p] : av;
            const int rowp = (s16 & 7) * 32 + group;      // valid row for s16<8
            const int m = rowp >> 6;                      // 0:kR 1:kW 2:eV 3:aV
            float xv = av + bias256[rowp];
            float e  = __expf((m == 2) ? -xv : 2.f * xv);
            float rcp = frcp(1.f + e);
            float act = (m == 2) ? rcp : 1.f - 2.f * rcp;
            if (s16 < 8) proj4[rowp] = act;

            if (wave == 0) {   // heads: group 0..3, reuse hx regs
                float a8 = 0.f;
                uint4 wh0 = *(const uint4*)&wheadu[group * 256 + s16 * 16 + 0];
                uint4 wh1 = *(const uint4*)&wheadu[group * 256 + s16 * 16 + 4];
                uint4 wh2 = *(const uint4*)&wheadu[group * 256 + s16 * 16 + 8];
                uint4 wh3 = *(const uint4*)&wheadu[group * 256 + s16 * 16 + 12];
                FD4(wh0, hx0, a8); FD4(wh1, hx1, a8);
                FD4(wh2, hx2, a8); FD4(wh3, hx3, a8);
                a8 = red16(a8);
                if (s16 == 0) {
                    float hv = a8 + bhead[group];
                    scal[group] = (group & 1) ? sigmoid_f(hv) : softplus_f(hv);
                }
            }
        }
        __syncthreads();   // B1

        // ---- Phase B: fused {dot_r, dot_w, norm} reductions -> packed exp scores ----
        {
            float4 kr4 = *(float4*)&proj4[sub * 4];
            float4 kw4 = *(float4*)&proj4[M_ + sub * 4];
            float snKR = fsqrt_(red16(dot4(kr4, kr4)));
            float snKW = fsqrt_(red16(dot4(kw4, kw4)));
            const bool isW = (sub == 1);
            float bta = isW ? scal[2] : scal[0];
            float snK = isW ? snKW : snKR;
            float eacc = 0.f;
            #pragma unroll
            for (int i = 0; i < 16; ++i) {
                int r = wave * 64 + i * 4 + g;
                float4 v = mreg[i];
                float c = dot4(kr4, v);
                float d = dot4(kw4, v);
                float n = dot4(v, v);
                float c2 = dpp_add<0xB1>(c), d2 = dpp_add<0xB1>(d), n2 = dpp_add<0xB1>(n);
                float c4 = dpp_add<0x4E>(c2), d4 = dpp_add<0x4E>(d2), n4 = dpp_add<0x4E>(n2);
                const int q = sub & 3;
                float z = (q == 0) ? c4 : (q == 1 ? d4 : n4);
                z = dpp_add<0x124>(z);
                z = dpp_add<0x128>(z);
                float nt = dpp_mov<0xAA>(z);   // norm total from quad-lane 2
                float sn = fsqrt_(nt);
                float ee = __expf(bta * z * frcp(snK * sn + EPS_));
                if (sub < 2) ((float*)&dotsRW[r])[sub] = ee;   // direct b32 halves
                eacc += (sub < 2) ? ee : 0.f;
            }
            float vsum = red64_pair(eacc);     // even: eR total, odd: eW total
            float vo = dpp_mov<0xB1>(vsum);
            if (lane == 0) wsumRW[wave] = make_float2(vsum, vo);
        }
        __syncthreads();   // B2

        // ---- Phase C: filters (all 64 lanes) + mem update + r_t partials ----
        {
            float2 ws = wsumRW[lane & 15];
            float totR = red16(ws.x);
            float totW = red16(ws.y);
            {
                const int r = wave * 64 + lane;
                float invR = frcp(totR), invW = frcp(totW);
                const int rm = (r + R_ - 1) & (R_ - 1), rp = (r + 1) & (R_ - 1);
                float gr = scal[1], gw = scal[3];
                float2 d0 = dotsRW[r];
                float2 dm = dotsRW[rm];
                float2 dp = dotsRW[rp];
                float2 p0 = ffb[cur][r];
                float2 pm = ffb[cur][rm];
                float2 pp = ffb[cur][rp];

                float f0 = gr * d0.x * invR + (1.f - gr) * p0.x;
                float fm = gr * dm.x * invR + (1.f - gr) * pm.x;
                float fp = gr * dp.x * invR + (1.f - gr) * pp.x;
                float q0 = gw * d0.y * invW + (1.f - gw) * p0.y;
                float qm = gw * dm.y * invW + (1.f - gw) * pm.y;
                float qp = gw * dp.y * invW + (1.f - gw) * pp.y;
                ffb[nxt][r] = make_float2(f0, q0);
                fwp[r] = make_float2(0.75f * f0 + 0.125f * (fm + fp),
                                     0.75f * q0 + 0.125f * (qm + qp));
            }
            __builtin_amdgcn_wave_barrier();   // same-wave LDS write->read ordering

            // preload all 16 filter pairs (independent ds_reads, one wait)
            float2 fw2[16];
            #pragma unroll
            for (int i = 0; i < 16; ++i)
                fw2[i] = fwp[wave * 64 + i * 4 + g];

            float4 e4 = *(float4*)&proj4[2 * M_ + sub * 4];
            float4 a4 = *(float4*)&proj4[3 * M_ + sub * 4];
            float rt0 = 0, rt1 = 0, rt2 = 0, rt3 = 0;
            #pragma unroll
            for (int i = 0; i < 16; ++i) {
                float wr = fw2[i].x, ww = fw2[i].y;
                float4 v = mreg[i];
                rt0 += wr * v.x; rt1 += wr * v.y; rt2 += wr * v.z; rt3 += wr * v.w;
                float4 nv;
                nv.x = v.x * (1.f - ww * e4.x) + ww * a4.x;
                nv.y = v.y * (1.f - ww * e4.y) + ww * a4.y;
                nv.z = v.z * (1.f - ww * e4.z) + ww * a4.z;
                nv.w = v.w * (1.f - ww * e4.w) + ww * a4.w;
                mreg[i] = nv;
            }
            rt0 += __shfl_xor(rt0, 16, 64); rt0 += __shfl_xor(rt0, 32, 64);
            rt1 += __shfl_xor(rt1, 16, 64); rt1 += __shfl_xor(rt1, 32, 64);
            rt2 += __shfl_xor(rt2, 16, 64); rt2 += __shfl_xor(rt2, 32, 64);
            rt3 += __shfl_xor(rt3, 16, 64); rt3 += __shfl_xor(rt3, 32, 64);
            if (g == 0) {
                rtp[sub * 4 + 0][wave] = rt0;
                rtp[sub * 4 + 1][wave] = rt1;
                rtp[sub * 4 + 2][wave] = rt2;
                rtp[sub * 4 + 3][wave] = rt3;
            }
        }
        __syncthreads();   // B3

        // ---- Phase D: rt reduction (2x b128) + full 64-dot from stride-36 LDS ----
        {
            float4 r0 = *(float4*)&rtp[lane][0];
            float4 r1 = *(float4*)&rtp[lane][4];
            float rsum = (r0.x + r0.y) + (r0.z + r0.w) + (r1.x + r1.y) + (r1.z + r1.w);
            rt8[wave][lane] = rsum;
            __builtin_amdgcn_wave_barrier();   // same-wave LDS write->read ordering

            float acc = 0.f;
            #pragma unroll
            for (int wd = 0; wd < 2; ++wd)
                #pragma unroll
                for (int c = 0; c < 4; ++c) {
                    uint4 wq = *(uint4*)&wrh[tid * 36 + wd * 16 + c * 4];
                    float4 ra = *(float4*)&rt8[wave][wd * 32 + c * 8];
                    float4 rb = *(float4*)&rt8[wave][wd * 32 + c * 8 + 4];
                    unsigned p0 = pk16(ra.x, ra.y), p1 = pk16(ra.z, ra.w);
                    unsigned p2 = pk16(rb.x, rb.y), p3 = pk16(rb.z, rb.w);
                    acc = fd2(wq.x, p0, acc); acc = fd2(wq.y, p1, acc);
                    acc = fd2(wq.z, p2, acc); acc = fd2(wq.w, p3, acc);
                }
            float xv = (float)__builtin_bit_cast(_Float16, xbits);
            float hv = fmaxf(xv + acc + breg, 0.f);
            unsigned short hb = bits16(hv);
            hh40[(tid >> 5) * 40 + (tid & 31)] = hb;
            h_all[(size_t)(b * T_ + t) * H_ + tid] = hb;
        }
        __syncthreads();   // B4
    }
}

extern "C" void kernel_launch(void* const* d_in, const int* in_sizes, int n_in,
                              void* d_out, int out_size, void* d_ws, size_t ws_size,
                              hipStream_t stream) {
    const float* x     = (const float*)d_in[0];
    const float* h0    = (const float*)d_in[1];
    const float* frf   = (const float*)d_in[2];
    const float* fwf   = (const float*)d_in[4];
    const float* m0    = (const float*)d_in[6];
    const float* Win   = (const float*)d_in[7];
    const float* bin   = (const float*)d_in[8];
    const float* Wread = (const float*)d_in[9];
    const float* bread = (const float*)d_in[10];
    const float* Wout  = (const float*)d_in[11];
    const float* bout  = (const float*)d_in[12];
    const float* Wkr   = (const float*)d_in[13];
    const float* bkr   = (const float*)d_in[14];
    const float* Wbr   = (const float*)d_in[15];
    const float* bbr   = (const float*)d_in[16];
    const float* Wgr   = (const float*)d_in[17];
    const float* bgr   = (const float*)d_in[18];
    const float* Wkw   = (const float*)d_in[19];
    const float* bkw   = (const float*)d_in[20];
    const float* Wbw   = (const float*)d_in[21];
    const float* bbw   = (const float*)d_in[22];
    const float* Wgw   = (const float*)d_in[23];
    const float* bgw   = (const float*)d_in[24];
    const float* We    = (const float*)d_in[25];
    const float* be    = (const float*)d_in[26];
    const float* Wa    = (const float*)d_in[27];
    const float* ba    = (const float*)d_in[28];

    char* ws = (char*)d_ws;
    unsigned short* xin_h  = (unsigned short*)(ws);                     // 8 MB
    unsigned short* h_allh = (unsigned short*)(ws + (8u << 20));        // 8 MB
    unsigned short* Wh     = (unsigned short*)(ws + (16u << 20));       // ~0.26 MB
    unsigned short* xh     = (unsigned short*)(ws + (17u << 20));       // 4 MB
    unsigned short* Winh   = (unsigned short*)(ws + (21u << 20));       // 0.25 MB
    unsigned short* Wouth  = (unsigned short*)(ws + (21u << 20) + (512u << 10)); // 0.25 MB

    prep<<<2433, 256, 0, stream>>>(x, Win, Wout, Wkr, Wkw, We, Wa,
                                   Wbr, Wgr, Wbw, Wgw, xh, Winh, Wouth, Wh);
    gemm_mfma<<<dim3(B_ * T_ / 128, H_ / 64), 256, 0, stream>>>(
        xh, Winh, bin, xin_h, B_ * T_, NIN, H_, 0);
    ntm_loop<<<B_, 512, 0, stream>>>(xin_h, h0, frf, fwf, m0,
        Wh, bkr, bkw, be, ba,
        bbr, bgr, bbw, bgw,
        Wread, bread, h_allh);
    gemm_mfma<<<dim3(B_ * T_ / 128, O_ / 64), 256, 0, stream>>>(
        h_allh, Wouth, bout, d_out, B_ * T_, H_, O_, 1);
}

// Round 16
// 785.481 us; speedup vs baseline: 1.1102x; 1.1102x over previous
//
#include <hip/hip_runtime.h>
#include <math.h>

#define B_   64
#define T_   128
#define NIN  256
#define H_   512
#define O_   256
#define M_   64
#define R_   512
#define EPS_ 1e-8f

typedef _Float16 h2 __attribute__((ext_vector_type(2)));
typedef _Float16 f16x8 __attribute__((ext_vector_type(8)));
typedef float f32x4 __attribute__((ext_vector_type(4)));

__device__ __forceinline__ float dot4(float4 a, float4 b) {
    return a.x*b.x + a.y*b.y + a.z*b.z + a.w*b.w;
}

__device__ __forceinline__ float frcp(float x) {
#if __has_builtin(__builtin_amdgcn_rcpf)
    return __builtin_amdgcn_rcpf(x);
#else
    return 1.f / x;
#endif
}
__device__ __forceinline__ float fsqrt_(float x) {
#if __has_builtin(__builtin_amdgcn_sqrtf)
    return __builtin_amdgcn_sqrtf(x);
#else
    return sqrtf(x);
#endif
}

__device__ __forceinline__ float fd2(unsigned wu, unsigned hu, float acc) {
#if __has_builtin(__builtin_amdgcn_fdot2)
    return __builtin_amdgcn_fdot2(__builtin_bit_cast(h2, wu),
                                  __builtin_bit_cast(h2, hu), acc, false);
#else
    h2 w = __builtin_bit_cast(h2, wu), h = __builtin_bit_cast(h2, hu);
    return acc + (float)w[0]*(float)h[0] + (float)w[1]*(float)h[1];
#endif
}
#define FD4(W, HX, A) { A = fd2(W.x, HX.x, A); A = fd2(W.y, HX.y, A); \
                        A = fd2(W.z, HX.z, A); A = fd2(W.w, HX.w, A); }

__device__ __forceinline__ unsigned pk16(float a, float b) {
    return __builtin_bit_cast(unsigned, __builtin_amdgcn_cvt_pkrtz(a, b));
}
__device__ __forceinline__ unsigned short bits16(float v) {
    return __builtin_bit_cast(unsigned short, (_Float16)v);
}

template<int CTRL>
__device__ __forceinline__ float dpp_add(float v) {
    int t = __builtin_amdgcn_update_dpp(0, __float_as_int(v), CTRL, 0xF, 0xF, false);
    return v + __int_as_float(t);
}
template<int CTRL>
__device__ __forceinline__ float dpp_mov(float v) {
    return __int_as_float(__builtin_amdgcn_update_dpp(0, __float_as_int(v), CTRL, 0xF, 0xF, false));
}
__device__ __forceinline__ float red16(float v) {
    v = dpp_add<0xB1>(v);    // quad_perm xor1
    v = dpp_add<0x4E>(v);    // quad_perm xor2
    v = dpp_add<0x124>(v);   // row_ror:4
    v = dpp_add<0x128>(v);   // row_ror:8
    return v;
}
__device__ __forceinline__ float red64_pair(float v) {
    v = dpp_add<0x4E>(v);    // xor2
    v = dpp_add<0x124>(v);   // ror4
    v = dpp_add<0x128>(v);   // ror8
    v += __shfl_xor(v, 16, 64);
    v += __shfl_xor(v, 32, 64);
    return v;
}
__device__ __forceinline__ float sigmoid_f(float x) { return frcp(1.f + __expf(-x)); }
__device__ __forceinline__ float softplus_f(float x){ return x > 20.f ? x : log1pf(__expf(x)); }

// ---------- Kernel 0: all fp32 -> fp16 conversions in one launch ----------
__global__ __launch_bounds__(256) void prep(
    const float* __restrict__ x, const float* __restrict__ Win,
    const float* __restrict__ Wout,
    const float* __restrict__ Wkr, const float* __restrict__ Wkw,
    const float* __restrict__ We,  const float* __restrict__ Wa,
    const float* __restrict__ Wbr, const float* __restrict__ Wgr,
    const float* __restrict__ Wbw, const float* __restrict__ Wgw,
    unsigned short* __restrict__ xh, unsigned short* __restrict__ Winh,
    unsigned short* __restrict__ Wouth, unsigned short* __restrict__ Wh)
{
    const int bid = blockIdx.x;
    if (bid == 2432) {   // scalar-head rows 256..259 of Wh
        const int idx = threadIdx.x * 8;
        #pragma unroll
        for (int k = 0; k < 8; ++k) {
            int i2 = idx + k;
            int mi2 = i2 >> 9;
            const float* s2 = mi2 == 0 ? Wbr : mi2 == 1 ? Wgr : mi2 == 2 ? Wbw : Wgw;
            Wh[256 * H_ + i2] = bits16(s2[i2 & (H_ - 1)]);
        }
        return;
    }
    const float* src; unsigned short* dst; int idx;
    if (bid < 2048)      { src = x;    dst = xh;    idx = bid * 1024 + threadIdx.x * 4; }
    else if (bid < 2176) { src = Win;  dst = Winh;  idx = (bid - 2048) * 1024 + threadIdx.x * 4; }
    else if (bid < 2304) { src = Wout; dst = Wouth; idx = (bid - 2176) * 1024 + threadIdx.x * 4; }
    else {
        const int mi = (bid - 2304) >> 5;
        src = mi == 0 ? Wkr : mi == 1 ? Wkw : mi == 2 ? We : Wa;
        dst = Wh + mi * 32768;
        idx = ((bid - 2304) & 31) * 1024 + threadIdx.x * 4;
    }
    float4 v = *(const float4*)&src[idx];
    ushort4 o;
    o.x = bits16(v.x); o.y = bits16(v.y); o.z = bits16(v.z); o.w = bits16(v.w);
    *(ushort4*)&dst[idx] = o;
}

// ---------- MFMA GEMM: C[M,N] = A_h[M,K] @ B_h[N,K]^T (+bias, opt sigmoid) ----------
__global__ __launch_bounds__(256) void gemm_mfma(
    const unsigned short* __restrict__ Ah, const unsigned short* __restrict__ Bh,
    const float* __restrict__ bias, void* __restrict__ outp,
    int M, int K, int N, int mode)
{
    const int tid  = threadIdx.x;
    const int wv   = tid >> 6, lane = tid & 63;
    const int m0   = blockIdx.x * 128 + wv * 32;
    const int n0   = blockIdx.y * 64;
    const int fr   = lane & 15, kg = lane >> 4;

    f32x4 acc[2][4] = {};
    const unsigned short* pa0 = Ah + (size_t)(m0 + fr) * K + kg * 8;
    const unsigned short* pa1 = pa0 + (size_t)16 * K;
    const unsigned short* pb  = Bh + (size_t)(n0 + fr) * K + kg * 8;

    for (int k0 = 0; k0 < K; k0 += 32) {
        f16x8 a0 = *(const f16x8*)(pa0 + k0);
        f16x8 a1 = *(const f16x8*)(pa1 + k0);
        #pragma unroll
        for (int j = 0; j < 4; ++j) {
            f16x8 bj = *(const f16x8*)(pb + (size_t)j * 16 * K + k0);
            acc[0][j] = __builtin_amdgcn_mfma_f32_16x16x32_f16(a0, bj, acc[0][j], 0, 0, 0);
            acc[1][j] = __builtin_amdgcn_mfma_f32_16x16x32_f16(a1, bj, acc[1][j], 0, 0, 0);
        }
    }
    #pragma unroll
    for (int j = 0; j < 4; ++j) {
        const int gcol = n0 + j * 16 + fr;
        const float bv = bias[gcol];
        #pragma unroll
        for (int i = 0; i < 2; ++i) {
            #pragma unroll
            for (int r = 0; r < 4; ++r) {
                const int grow = m0 + i * 16 + kg * 4 + r;
                float v = acc[i][j][r] + bv;
                if (mode == 0)
                    ((unsigned short*)outp)[(size_t)grow * N + gcol] = bits16(v);
                else
                    ((float*)outp)[(size_t)grow * N + gcol] = sigmoid_f(v);
            }
        }
    }
}

// ---------- Kernel 2: recurrent loop, 512 threads (8 waves) ----------
__global__ __launch_bounds__(512, 2) void ntm_loop(
    const unsigned short* __restrict__ xin_h,
    const float* __restrict__ h0,
    const float* __restrict__ frf0, const float* __restrict__ fwf0,
    const float* __restrict__ m0,
    const unsigned short* __restrict__ Wh,      // fp16 [256 proj rows; 4 head rows]
    const float* __restrict__ bkr_g, const float* __restrict__ bkw_g,
    const float* __restrict__ be_g,  const float* __restrict__ ba_g,
    const float* __restrict__ bbr_g, const float* __restrict__ bgr_g,
    const float* __restrict__ bbw_g, const float* __restrict__ bgw_g,
    const float* __restrict__ Wread, const float* __restrict__ bread_g,
    unsigned short* __restrict__ h_all)
{
    __shared__ __align__(16) unsigned short hh40[16 * 40];  // fp16 h, stride-40 rows
    __shared__ __align__(16) unsigned wrh[R_ * 36];         // fp16 Wread, stride-36 (72 KB)
    __shared__ __align__(16) float2 ffb[2][R_];             // {frf,fwf} double buffer (8 KB)
    __shared__ __align__(16) float2 dotsRW[R_];             // {eR,eW} (4 KB)
    __shared__ __align__(16) float2 fwp[R_];                // {w_read,w_write} (4 KB)
    __shared__ __align__(16) float proj4[4 * M_];           // kR|kW|eV|aV flat [256]
    __shared__ __align__(16) float rtp[8][M_];              // per-wave rt partials (2 KB)
    __shared__ __align__(16) float rt8[8][M_];              // per-wave reduced rt (2 KB)
    __shared__ __align__(16) float2 wsumRW[16];             // [8..15] stay zero
    __shared__ __align__(16) float bias256[4 * M_];
    __shared__ __align__(16) unsigned wheadu[4 * H_ / 2];   // 4 head rows fp16 (4 KB)
    __shared__ float bhead[4];
    __shared__ float scal[4];   // beta_r, g_r, beta_w, g_w

    const int b    = blockIdx.x;
    const int tid  = threadIdx.x;
    const int wave = tid >> 6, lane = tid & 63;
    const int g    = lane >> 4, sub = lane & 15;
    const int group = tid >> 4, s16 = tid & 15;   // phase-A: 32 groups x 16 lanes

    // ---- init ----
    const float* mg = m0 + (size_t)b * (R_ * M_);
    float4 mreg[16];                            // 64 regs: rows wave*64 + i*4 + g
    #pragma unroll
    for (int i = 0; i < 16; ++i)
        mreg[i] = *(const float4*)&mg[(wave * 64 + i * 4 + g) * M_ + sub * 4];

    // projection weights in registers: 8 passes x 4 uint4 = 128 regs
    uint4 w16[32];
    #pragma unroll
    for (int p = 0; p < 8; ++p)
        #pragma unroll
        for (int j = 0; j < 4; ++j)
            w16[p * 4 + j] = *(const uint4*)&Wh[(size_t)(p * 32 + group) * H_ + s16 * 32 + j * 8];

    hh40[(tid >> 5) * 40 + (tid & 31)] = bits16(h0[b * H_ + tid]);
    ffb[0][tid] = make_float2(frf0[b * R_ + tid], fwf0[b * R_ + tid]);
    if (tid < M_) {
        bias256[tid]          = bkr_g[tid];
        bias256[M_ + tid]     = bkw_g[tid];
        bias256[2 * M_ + tid] = be_g[tid];
        bias256[3 * M_ + tid] = ba_g[tid];
    }
    if (tid >= 8 && tid < 16) wsumRW[tid] = make_float2(0.f, 0.f);
    wheadu[tid * 2]     = ((const unsigned*)&Wh[256 * H_])[tid * 2];
    wheadu[tid * 2 + 1] = ((const unsigned*)&Wh[256 * H_])[tid * 2 + 1];
    if (tid < 4) bhead[tid] = (tid == 0 ? bbr_g : tid == 1 ? bgr_g : tid == 2 ? bbw_g : bgw_g)[0];

    // Wread -> LDS fp16, stride-36 rows; one full row per thread
    {
        const float* wrp = Wread + (size_t)tid * M_;
        #pragma unroll
        for (int wd = 0; wd < 2; ++wd)
            #pragma unroll
            for (int c = 0; c < 4; ++c) {
                float4 wa = *(const float4*)&wrp[wd * 32 + c * 8];
                float4 wb = *(const float4*)&wrp[wd * 32 + c * 8 + 4];
                uint4 o;
                o.x = pk16(wa.x, wa.y); o.y = pk16(wa.z, wa.w);
                o.z = pk16(wb.x, wb.y); o.w = pk16(wb.z, wb.w);
                *(uint4*)&wrh[tid * 36 + wd * 16 + c * 4] = o;
            }
    }
    const float breg = bread_g[tid];
    __syncthreads();

    for (int t = 0; t < T_; ++t) {
        const int cur = t & 1, nxt = cur ^ 1;

        // ---- Phase A: 8-pass projections + heads (wave 0) ----
        unsigned short xbits = xin_h[(size_t)(b * T_ + t) * H_ + tid];
        {
            uint4 hx0 = *(const uint4*)&hh40[s16 * 40 + 0];
            uint4 hx1 = *(const uint4*)&hh40[s16 * 40 + 8];
            uint4 hx2 = *(const uint4*)&hh40[s16 * 40 + 16];
            uint4 hx3 = *(const uint4*)&hh40[s16 * 40 + 24];
            float a[8];
            #pragma unroll
            for (int p = 0; p < 8; ++p) {
                float acc = 0.f;
                FD4(w16[p * 4 + 0], hx0, acc);
                FD4(w16[p * 4 + 1], hx1, acc);
                FD4(w16[p * 4 + 2], hx2, acc);
                FD4(w16[p * 4 + 3], hx3, acc);
                a[p] = red16(acc);
            }
            float av = a[0];
            #pragma unroll
            for (int p = 1; p < 8; ++p) av = (s16 == p) ? a[p] : av;
            const int rowp = (s16 & 7) * 32 + group;      // valid row for s16<8
            const int m = rowp >> 6;                      // 0:kR 1:kW 2:eV 3:aV
            float xv = av + bias256[rowp];
            float e  = __expf((m == 2) ? -xv : 2.f * xv);
            float rcp = frcp(1.f + e);
            float act = (m == 2) ? rcp : 1.f - 2.f * rcp;
            if (s16 < 8) proj4[rowp] = act;

            if (wave == 0) {   // heads: group 0..3, reuse hx regs
                float a8 = 0.f;
                uint4 wh0 = *(const uint4*)&wheadu[group * 256 + s16 * 16 + 0];
                uint4 wh1 = *(const uint4*)&wheadu[group * 256 + s16 * 16 + 4];
                uint4 wh2 = *(const uint4*)&wheadu[group * 256 + s16 * 16 + 8];
                uint4 wh3 = *(const uint4*)&wheadu[group * 256 + s16 * 16 + 12];
                FD4(wh0, hx0, a8); FD4(wh1, hx1, a8);
                FD4(wh2, hx2, a8); FD4(wh3, hx3, a8);
                a8 = red16(a8);
                if (s16 == 0) {
                    float hv = a8 + bhead[group];
                    scal[group] = (group & 1) ? sigmoid_f(hv) : softplus_f(hv);
                }
            }
        }
        __syncthreads();   // B1

        // ---- Phase B: fused {dot_r, dot_w, norm} reductions -> packed exp scores ----
        {
            float4 kr4 = *(float4*)&proj4[sub * 4];
            float4 kw4 = *(float4*)&proj4[M_ + sub * 4];
            float snKR = fsqrt_(red16(dot4(kr4, kr4)));
            float snKW = fsqrt_(red16(dot4(kw4, kw4)));
            const bool isW = (sub == 1);
            float bta = isW ? scal[2] : scal[0];
            float snK = isW ? snKW : snKR;
            float eacc = 0.f;
            #pragma unroll
            for (int i = 0; i < 16; ++i) {
                int r = wave * 64 + i * 4 + g;
                float4 v = mreg[i];
                float c = dot4(kr4, v);
                float d = dot4(kw4, v);
                float n = dot4(v, v);
                float c2 = dpp_add<0xB1>(c), d2 = dpp_add<0xB1>(d), n2 = dpp_add<0xB1>(n);
                float c4 = dpp_add<0x4E>(c2), d4 = dpp_add<0x4E>(d2), n4 = dpp_add<0x4E>(n2);
                const int q = sub & 3;
                float z = (q == 0) ? c4 : (q == 1 ? d4 : n4);
                z = dpp_add<0x124>(z);
                z = dpp_add<0x128>(z);
                float nt = dpp_mov<0xAA>(z);   // norm total from quad-lane 2
                float sn = fsqrt_(nt);
                float ee = __expf(bta * z * frcp(snK * sn + EPS_));
                float eo = dpp_mov<0xB1>(ee);  // partner's value
                if (sub == 0) dotsRW[r] = make_float2(ee, eo);
                eacc += (sub < 2) ? ee : 0.f;
            }
            float vsum = red64_pair(eacc);     // even: eR total, odd: eW total
            float vo = dpp_mov<0xB1>(vsum);
            if (lane == 0) wsumRW[wave] = make_float2(vsum, vo);
        }
        __syncthreads();   // B2

        // ---- Phase C: filters (all 64 lanes) + mem update + r_t partials ----
        {
            float2 ws = wsumRW[lane & 15];
            float totR = red16(ws.x);
            float totW = red16(ws.y);
            {
                const int r = wave * 64 + lane;
                float invR = frcp(totR), invW = frcp(totW);
                const int rm = (r + R_ - 1) & (R_ - 1), rp = (r + 1) & (R_ - 1);
                float gr = scal[1], gw = scal[3];
                float2 d0 = dotsRW[r];
                float2 dm = dotsRW[rm];
                float2 dp = dotsRW[rp];
                float2 p0 = ffb[cur][r];
                float2 pm = ffb[cur][rm];
                float2 pp = ffb[cur][rp];

                float f0 = gr * d0.x * invR + (1.f - gr) * p0.x;
                float fm = gr * dm.x * invR + (1.f - gr) * pm.x;
                float fp = gr * dp.x * invR + (1.f - gr) * pp.x;
                float q0 = gw * d0.y * invW + (1.f - gw) * p0.y;
                float qm = gw * dm.y * invW + (1.f - gw) * pm.y;
                float qp = gw * dp.y * invW + (1.f - gw) * pp.y;
                ffb[nxt][r] = make_float2(f0, q0);
                fwp[r] = make_float2(0.75f * f0 + 0.125f * (fm + fp),
                                     0.75f * q0 + 0.125f * (qm + qp));
            }
            __builtin_amdgcn_wave_barrier();   // same-wave LDS write->read ordering

            // preload all 16 filter pairs (independent ds_reads, one wait)
            float2 fw2[16];
            #pragma unroll
            for (int i = 0; i < 16; ++i)
                fw2[i] = fwp[wave * 64 + i * 4 + g];

            float4 e4 = *(float4*)&proj4[2 * M_ + sub * 4];
            float4 a4 = *(float4*)&proj4[3 * M_ + sub * 4];
            float rt0 = 0, rt1 = 0, rt2 = 0, rt3 = 0;
            #pragma unroll
            for (int i = 0; i < 16; ++i) {
                float wr = fw2[i].x, ww = fw2[i].y;
                float4 v = mreg[i];
                rt0 += wr * v.x; rt1 += wr * v.y; rt2 += wr * v.z; rt3 += wr * v.w;
                float4 nv;
                nv.x = v.x * (1.f - ww * e4.x) + ww * a4.x;
                nv.y = v.y * (1.f - ww * e4.y) + ww * a4.y;
                nv.z = v.z * (1.f - ww * e4.z) + ww * a4.z;
                nv.w = v.w * (1.f - ww * e4.w) + ww * a4.w;
                mreg[i] = nv;
            }
            rt0 += __shfl_xor(rt0, 16, 64); rt0 += __shfl_xor(rt0, 32, 64);
            rt1 += __shfl_xor(rt1, 16, 64); rt1 += __shfl_xor(rt1, 32, 64);
            rt2 += __shfl_xor(rt2, 16, 64); rt2 += __shfl_xor(rt2, 32, 64);
            rt3 += __shfl_xor(rt3, 16, 64); rt3 += __shfl_xor(rt3, 32, 64);
            if (g == 0)
                *(float4*)&rtp[wave][sub * 4] = make_float4(rt0, rt1, rt2, rt3);
        }
        __syncthreads();   // B3

        // ---- Phase D: wave-private rt reduction + full 64-dot from stride-36 LDS ----
        {
            float rsum = rtp[0][lane] + rtp[1][lane] + rtp[2][lane] + rtp[3][lane]
                       + rtp[4][lane] + rtp[5][lane] + rtp[6][lane] + rtp[7][lane];
            rt8[wave][lane] = rsum;
            __builtin_amdgcn_wave_barrier();   // same-wave LDS write->read ordering

            float acc = 0.f;
            #pragma unroll
            for (int wd = 0; wd < 2; ++wd)
                #pragma unroll
                for (int c = 0; c < 4; ++c) {
                    uint4 wq = *(uint4*)&wrh[tid * 36 + wd * 16 + c * 4];
                    float4 ra = *(float4*)&rt8[wave][wd * 32 + c * 8];
                    float4 rb = *(float4*)&rt8[wave][wd * 32 + c * 8 + 4];
                    unsigned p0 = pk16(ra.x, ra.y), p1 = pk16(ra.z, ra.w);
                    unsigned p2 = pk16(rb.x, rb.y), p3 = pk16(rb.z, rb.w);
                    acc = fd2(wq.x, p0, acc); acc = fd2(wq.y, p1, acc);
                    acc = fd2(wq.z, p2, acc); acc = fd2(wq.w, p3, acc);
                }
            float xv = (float)__builtin_bit_cast(_Float16, xbits);
            float hv = fmaxf(xv + acc + breg, 0.f);
            unsigned short hb = bits16(hv);
            hh40[(tid >> 5) * 40 + (tid & 31)] = hb;
            h_all[(size_t)(b * T_ + t) * H_ + tid] = hb;
        }
        __syncthreads();   // B4
    }
}

extern "C" void kernel_launch(void* const* d_in, const int* in_sizes, int n_in,
                              void* d_out, int out_size, void* d_ws, size_t ws_size,
                              hipStream_t stream) {
    const float* x     = (const float*)d_in[0];
    const float* h0    = (const float*)d_in[1];
    const float* frf   = (const float*)d_in[2];
    const float* fwf   = (const float*)d_in[4];
    const float* m0    = (const float*)d_in[6];
    const float* Win   = (const float*)d_in[7];
    const float* bin   = (const float*)d_in[8];
    const float* Wread = (const float*)d_in[9];
    const float* bread = (const float*)d_in[10];
    const float* Wout  = (const float*)d_in[11];
    const float* bout  = (const float*)d_in[12];
    const float* Wkr   = (const float*)d_in[13];
    const float* bkr   = (const float*)d_in[14];
    const float* Wbr   = (const float*)d_in[15];
    const float* bbr   = (const float*)d_in[16];
    const float* Wgr   = (const float*)d_in[17];
    const float* bgr   = (const float*)d_in[18];
    const float* Wkw   = (const float*)d_in[19];
    const float* bkw   = (const float*)d_in[20];
    const float* Wbw   = (const float*)d_in[21];
    const float* bbw   = (const float*)d_in[22];
    const float* Wgw   = (const float*)d_in[23];
    const float* bgw   = (const float*)d_in[24];
    const float* We    = (const float*)d_in[25];
    const float* be    = (const float*)d_in[26];
    const float* Wa    = (const float*)d_in[27];
    const float* ba    = (const float*)d_in[28];

    char* ws = (char*)d_ws;
    unsigned short* xin_h  = (unsigned short*)(ws);                     // 8 MB
    unsigned short* h_allh = (unsigned short*)(ws + (8u << 20));        // 8 MB
    unsigned short* Wh     = (unsigned short*)(ws + (16u << 20));       // ~0.26 MB
    unsigned short* xh     = (unsigned short*)(ws + (17u << 20));       // 4 MB
    unsigned short* Winh   = (unsigned short*)(ws + (21u << 20));       // 0.25 MB
    unsigned short* Wouth  = (unsigned short*)(ws + (21u << 20) + (512u << 10)); // 0.25 MB

    prep<<<2433, 256, 0, stream>>>(x, Win, Wout, Wkr, Wkw, We, Wa,
                                   Wbr, Wgr, Wbw, Wgw, xh, Winh, Wouth, Wh);
    gemm_mfma<<<dim3(B_ * T_ / 128, H_ / 64), 256, 0, stream>>>(
        xh, Winh, bin, xin_h, B_ * T_, NIN, H_, 0);
    ntm_loop<<<B_, 512, 0, stream>>>(xin_h, h0, frf, fwf, m0,
        Wh, bkr, bkw, be, ba,
        bbr, bgr, bbw, bgw,
        Wread, bread, h_allh);
    gemm_mfma<<<dim3(B_ * T_ / 128, O_ / 64), 256, 0, stream>>>(
        h_allh, Wouth, bout, d_out, B_ * T_, H_, O_, 1);
}